// Round 1
// baseline (5952.443 us; speedup 1.0000x reference)
//
#include <hip/hip_runtime.h>

// ---------------------------------------------------------------------------
// RecurrentActorCritic on MI355X.
// Layout / sizes: B=128, T=256, F=128, H=256, 4H=1024, W=512, A=8.
// d_out (float): mean[1024] | log_std[8] | value[128] | c0n[32768] | h0n | c1n | h1n
// ---------------------------------------------------------------------------

typedef __attribute__((ext_vector_type(8))) short  frag8;   // 8 bf16 (4 VGPR)
typedef __attribute__((ext_vector_type(4))) float  f32x4;
typedef __attribute__((ext_vector_type(16))) float f32x16;
typedef unsigned short u16;
typedef unsigned int   u32;

// workspace layout (bytes)
#define WS_BAR   0                                   // 2 x 8KB barrier regions
#define WS_XT    (16384)                             // (T,B,F) bf16: 8.4MB
#define WS_YS0   (WS_XT + 128*256*128*2)             // (T,B,H) bf16: 16.8MB
#define WS_P     (16384)                             // 16.8MB, aliases XT+YS0 (dead)
#define WS_YS1   (WS_YS0 + 128*256*256*2)            // (T,B,H) bf16: 16.8MB
#define WS_HB0   (WS_YS1 + 128*256*256*2)            // 2x(128,256) bf16
#define WS_HB1   (WS_HB0 + 2*128*256*2)
#define WS_H0M   (WS_HB1 + 2*128*256*2)              // (128,1024) bf16
#define WS_V1M   (WS_H0M + 128*1024*2)               // (128,1024) bf16

__device__ __forceinline__ u16 f2b(float f) {
  u32 u = __builtin_bit_cast(u32, f);
  u32 r = (u + 0x7fffu + ((u >> 16) & 1u)) >> 16;   // RNE
  return (u16)r;
}
__device__ __forceinline__ float b2f(u16 b) {
  return __builtin_bit_cast(float, (u32)b << 16);
}
__device__ __forceinline__ float sigm(float x) { return 1.0f / (1.0f + __expf(-x)); }
__device__ __forceinline__ float tanh_(float x) {
  x = fminf(fmaxf(x, -15.0f), 15.0f);
  float e = __expf(2.0f * x);
  return (e - 1.0f) / (e + 1.0f);
}

// ---------------- grid barrier (monotonic slot/gen, AGENT scope) -----------
__device__ __forceinline__ void gridbar(u32* bar, u32 val, int nblk) {
  __syncthreads();
  const int tid = threadIdx.x;
  if (tid == 0) {
    __hip_atomic_store(bar + (blockIdx.x << 4), val, __ATOMIC_RELEASE,
                       __HIP_MEMORY_SCOPE_AGENT);
  }
  if (blockIdx.x == 0) {
    if (tid < nblk) {
      while (__hip_atomic_load(bar + (tid << 4), __ATOMIC_ACQUIRE,
                               __HIP_MEMORY_SCOPE_AGENT) < val)
        __builtin_amdgcn_s_sleep(2);
    }
    __syncthreads();
    if (tid == 0)
      __hip_atomic_store(bar + 1024, val, __ATOMIC_RELEASE,
                         __HIP_MEMORY_SCOPE_AGENT);
  }
  if (tid == 0) {
    while (__hip_atomic_load(bar + 1024, __ATOMIC_ACQUIRE,
                             __HIP_MEMORY_SCOPE_AGENT) < val)
      __builtin_amdgcn_s_sleep(2);
  }
  __syncthreads();
}

// ---------------- K0: x (B,T,F) f32 -> xT (T,B,F) bf16 ---------------------
__global__ void convert_x_kernel(const float* __restrict__ x, u16* __restrict__ xT) {
  int g = blockIdx.x * 256 + threadIdx.x;          // 1,048,576 threads, 4 elems each
  int f4 = g & 31, rem = g >> 5;                   // rem = t*128 + b
  int t = rem >> 7, b = rem & 127;
  const float4 v = *reinterpret_cast<const float4*>(x + ((size_t)(b * 256 + t)) * 128 + f4 * 4);
  ushort4 ov;
  ov.x = f2b(v.x); ov.y = f2b(v.y); ov.z = f2b(v.z); ov.w = f2b(v.w);
  *reinterpret_cast<ushort4*>(xT + (size_t)rem * 128 + f4 * 4) = ov;
}

// ---------------- persistent LSTM layer kernel -----------------------------
// grid = 16 blocks (each owns 16 hidden dims = 64 gate cols), 256 threads.
// Wave w owns batch rows [32w, 32w+32). Weights resident in VGPRs.
// Gate-col packing: tile0 = [i|f] (cols g*16+n, g=0,1), tile1 = [g|o].
template <int FIN>
__launch_bounds__(256, 1)
__global__ void lstm_kernel(const u16* __restrict__ xsrc,   // (T,128,FIN) bf16
                            const float* __restrict__ Wi,   // (FIN,1024)
                            const float* __restrict__ Wh,   // (256,1024)
                            const float* __restrict__ bias, // (1024)
                            const float* __restrict__ c0,   // (128,256)
                            const float* __restrict__ h0,   // (128,256)
                            u16* __restrict__ hbuf,         // (2,128,256) bf16
                            u16* __restrict__ ys,           // (T,128,256) bf16
                            float* __restrict__ cOut,
                            float* __restrict__ hOut,
                            u32* __restrict__ bar) {
  constexpr int K = FIN + 256;
  constexpr int NKT = K / 16;
  const int tid = threadIdx.x;
  const int wv  = tid >> 6;          // wave 0..3
  const int l   = tid & 63;
  const int cg  = blockIdx.x;        // 0..15
  const int hdbase = cg << 4;

  // ---- weights -> registers (B fragments). frag col c = l&31 (+32 for tile1).
  frag8 bw0[NKT], bw1[NKT];
  {
    const int cl  = l & 31;
    const int g0 = cl >> 4, n0 = cl & 15;
    const int gcol0 = g0 * 256 + hdbase + n0;        // gates i/f
    const int gcol1 = (2 + g0) * 256 + hdbase + n0;  // gates g/o
    const int kh = (l >> 5) * 8;
#pragma unroll
    for (int kt = 0; kt < NKT; ++kt) {
      frag8 f0, f1;
#pragma unroll
      for (int j = 0; j < 8; ++j) {
        int k = kt * 16 + kh + j;
        float a0 = (k < FIN) ? Wi[(size_t)k * 1024 + gcol0] : Wh[(size_t)(k - FIN) * 1024 + gcol0];
        float a1 = (k < FIN) ? Wi[(size_t)k * 1024 + gcol1] : Wh[(size_t)(k - FIN) * 1024 + gcol1];
        f0[j] = (short)f2b(a0);
        f1[j] = (short)f2b(a1);
      }
      bw0[kt] = f0; bw1[kt] = f1;
    }
  }

  const int hd = hdbase + (l & 15);
  const float bi_i = bias[0 * 256 + hd];
  const float bi_f = bias[1 * 256 + hd];
  const float bi_g = bias[2 * 256 + hd];
  const float bi_o = bias[3 * 256 + hd];

  // c state in registers: reg r -> row rbase + (r&3) + 8*(r>>2)
  const int rbase = 32 * wv + 4 * (l >> 5);
  float cst[16];
#pragma unroll
  for (int r = 0; r < 16; ++r) {
    int row = rbase + (r & 3) + 8 * (r >> 2);
    cst[r] = c0[row * 256 + hd];
  }

  // init h double-buffer[0] with bf16(h0) (this block's hd slice, all rows)
  for (int e = tid; e < 128 * 16; e += 256) {
    int b = e >> 4;
    int hh = hdbase + (e & 15);
    hbuf[b * 256 + hh] = f2b(h0[b * 256 + hh]);
  }
  gridbar(bar, 1u, 16);

  const int arow = 32 * wv + (l & 31);
  const int kh8  = (l >> 5) * 8;
  const bool hiLane = (l & 16) != 0;
  const bool writer = ((l & 31) < 16);

#pragma unroll 1
  for (int t = 0; t < 256; ++t) {
    const u16* hsrc = hbuf + (t & 1) * (128 * 256);
    u16*       hdst = hbuf + ((t + 1) & 1) * (128 * 256);
    const u16* xrow = xsrc + ((size_t)t * 128 + arow) * FIN;
    const u16* hrow = hsrc + arow * 256;

    f32x16 acc0 = {}; f32x16 acc1 = {};
#pragma unroll
    for (int kt = 0; kt < NKT; ++kt) {
      int kb = kt * 16 + kh8;
      frag8 a;
      if (kt * 16 < FIN) a = *reinterpret_cast<const frag8*>(xrow + kb);
      else               a = *reinterpret_cast<const frag8*>(hrow + (kb - FIN));
      acc0 = __builtin_amdgcn_mfma_f32_32x32x16_bf16(a, bw0[kt], acc0, 0, 0, 0);
      acc1 = __builtin_amdgcn_mfma_f32_32x32x16_bf16(a, bw1[kt], acc1, 0, 0, 0);
    }

    // exchange gate pairs within lane pairs (l ^ 16) and update state
#pragma unroll
    for (int r = 0; r < 16; ++r) {
      float v0 = acc0[r], v1 = acc1[r];
      float p0 = __shfl_xor(v0, 16);
      float p1 = __shfl_xor(v1, 16);
      float zi = (hiLane ? p0 : v0) + bi_i;
      float zf = (hiLane ? v0 : p0) + bi_f;
      float zg = (hiLane ? p1 : v1) + bi_g;
      float zo = (hiLane ? v1 : p1) + bi_o;
      float cn = sigm(zf) * cst[r] + sigm(zi) * tanh_(zg);
      float hn = sigm(zo) * tanh_(cn);
      cst[r] = cn;
      if (writer) {
        int row = rbase + (r & 3) + 8 * (r >> 2);
        u16 hb = f2b(hn);
        hdst[row * 256 + hd] = hb;
        ys[((size_t)t * 128 + row) * 256 + hd] = hb;
        if (t == 255) {
          cOut[row * 256 + hd] = cn;
          hOut[row * 256 + hd] = hn;
        }
      }
    }
    if (t < 255) gridbar(bar, (u32)(t + 2), 16);
  }
}

// ---------------- heads: big GEMM (flat @ [Wv0|Wm0]), K-split --------------
// grid = 512 blocks: bx = nb*32 + kb ; nb 0..7 value, 8..15 mean; kb 0..31.
__launch_bounds__(256, 2)
__global__ void head_gemm_kernel(const u16* __restrict__ flatT,  // ys1 (T,128,256)
                                 const float* __restrict__ Wv0,
                                 const float* __restrict__ Wm0,
                                 float* __restrict__ P) {
  const int bx = blockIdx.x;
  const int nb = bx >> 5, kb = bx & 31;
  const float* W = (nb >> 3) ? Wm0 : Wv0;
  const int ncb = (nb & 7) * 64;
  const int tid = threadIdx.x;
  const int wv = tid >> 6, l = tid & 63;
  const int lrow = l & 15, lk = (l >> 4) * 8;
  f32x4 acc[2][4] = {};
  const int kbase = kb * 2048;
#pragma unroll 2
  for (int ks = 0; ks < 64; ++ks) {
    int k0 = kbase + ks * 32;
    int t = k0 >> 8, h = k0 & 255;
    frag8 a[2];
#pragma unroll
    for (int mi = 0; mi < 2; ++mi) {
      int row = (2 * wv + mi) * 16 + lrow;
      a[mi] = *reinterpret_cast<const frag8*>(flatT + ((size_t)t * 128 + row) * 256 + h + lk);
    }
#pragma unroll
    for (int nt = 0; nt < 4; ++nt) {
      int col = ncb + nt * 16 + lrow;
      const float* wp = W + (size_t)(k0 + lk) * 512 + col;
      frag8 bfrag;
#pragma unroll
      for (int j = 0; j < 8; ++j) bfrag[j] = (short)f2b(wp[(size_t)j * 512]);
      acc[0][nt] = __builtin_amdgcn_mfma_f32_16x16x32_bf16(a[0], bfrag, acc[0][nt], 0, 0, 0);
      acc[1][nt] = __builtin_amdgcn_mfma_f32_16x16x32_bf16(a[1], bfrag, acc[1][nt], 0, 0, 0);
    }
  }
  float* Pb = P + (size_t)bx * 8192;
#pragma unroll
  for (int mi = 0; mi < 2; ++mi)
#pragma unroll
    for (int nt = 0; nt < 4; ++nt)
#pragma unroll
      for (int r = 0; r < 4; ++r) {
        int row = (2 * wv + mi) * 16 + (l >> 4) * 4 + r;
        int nl = nt * 16 + lrow;
        Pb[row * 64 + nl] = acc[mi][nt][r];
      }
}

// reduce K-partials, add bias, tanh -> H0 (128,1024) bf16 ([V0|M0])
__global__ void head_reduce_kernel(const float* __restrict__ P,
                                   const float* __restrict__ bv0,
                                   const float* __restrict__ bm0,
                                   u16* __restrict__ H0) {
  int o = blockIdx.x * 256 + threadIdx.x;   // 131072 outputs
  int row = o >> 10, gcol = o & 1023;
  int nb = gcol >> 6, nl = gcol & 63;
  float s = 0.f;
#pragma unroll
  for (int kb = 0; kb < 32; ++kb)
    s += P[(size_t)(nb * 32 + kb) * 8192 + row * 64 + nl];
  s += (gcol < 512) ? bv0[gcol] : bm0[gcol - 512];
  H0[row * 1024 + gcol] = f2b(tanh_(s));
}

// second hidden layer for both heads: V1M (128,1024) bf16 ([V1|M1])
__launch_bounds__(256, 2)
__global__ void head_mid_kernel(const u16* __restrict__ H0,
                                const float* __restrict__ Wv1,
                                const float* __restrict__ Wm1,
                                const float* __restrict__ bv1,
                                const float* __restrict__ bm1,
                                u16* __restrict__ V1M) {
  const int nb = blockIdx.x;        // 0..15
  const int head = nb >> 3;
  const int ncb = (nb & 7) * 64;
  const float* W = head ? Wm1 : Wv1;
  const float* bsrc = head ? bm1 : bv1;
  const int tid = threadIdx.x, wv = tid >> 6, l = tid & 63;
  const int lrow = l & 15, lk = (l >> 4) * 8;
  const int aoff = head * 512;
  f32x4 acc[2][4] = {};
#pragma unroll 2
  for (int ks = 0; ks < 16; ++ks) {
    int k0 = ks * 32;
    frag8 a[2];
#pragma unroll
    for (int mi = 0; mi < 2; ++mi) {
      int row = (2 * wv + mi) * 16 + lrow;
      a[mi] = *reinterpret_cast<const frag8*>(H0 + row * 1024 + aoff + k0 + lk);
    }
#pragma unroll
    for (int nt = 0; nt < 4; ++nt) {
      int col = ncb + nt * 16 + lrow;
      const float* wp = W + (size_t)(k0 + lk) * 512 + col;
      frag8 bfrag;
#pragma unroll
      for (int j = 0; j < 8; ++j) bfrag[j] = (short)f2b(wp[(size_t)j * 512]);
      acc[0][nt] = __builtin_amdgcn_mfma_f32_16x16x32_bf16(a[0], bfrag, acc[0][nt], 0, 0, 0);
      acc[1][nt] = __builtin_amdgcn_mfma_f32_16x16x32_bf16(a[1], bfrag, acc[1][nt], 0, 0, 0);
    }
  }
#pragma unroll
  for (int mi = 0; mi < 2; ++mi)
#pragma unroll
    for (int nt = 0; nt < 4; ++nt)
#pragma unroll
      for (int r = 0; r < 4; ++r) {
        int row = (2 * wv + mi) * 16 + (l >> 4) * 4 + r;
        int cl = ncb + nt * 16 + lrow;
        float z = acc[mi][nt][r] + bsrc[cl];
        V1M[row * 1024 + head * 512 + cl] = f2b(tanh_(z));
      }
}

// final projections: mean (128x8), value (128), log_std copy
__global__ void head_final_kernel(const u16* __restrict__ V1M,
                                  const float* __restrict__ Wv2,
                                  const float* __restrict__ bv2,
                                  const float* __restrict__ Wm2,
                                  const float* __restrict__ bm2,
                                  const float* __restrict__ log_std,
                                  float* __restrict__ out) {
  int tid = threadIdx.x;   // 1024 threads
  {
    int row = tid >> 3, a = tid & 7;
    float s = 0.f;
    for (int k = 0; k < 512; ++k)
      s += b2f(V1M[row * 1024 + 512 + k]) * Wm2[k * 8 + a];
    out[row * 8 + a] = s + bm2[a];
  }
  if (tid < 128) {
    float s = 0.f;
    for (int k = 0; k < 512; ++k)
      s += b2f(V1M[tid * 1024 + k]) * Wv2[k];
    out[1032 + tid] = s + bv2[0];
  }
  if (tid < 8) out[1024 + tid] = log_std[tid];
}

// ---------------------------------------------------------------------------
extern "C" void kernel_launch(void* const* d_in, const int* in_sizes, int n_in,
                              void* d_out, int out_size, void* d_ws, size_t ws_size,
                              hipStream_t stream) {
  const float* x    = (const float*)d_in[0];
  const float* c0   = (const float*)d_in[1];
  const float* h0   = (const float*)d_in[2];
  const float* c1   = (const float*)d_in[3];
  const float* h1   = (const float*)d_in[4];
  const float* Wi0  = (const float*)d_in[5];
  const float* Wh0  = (const float*)d_in[6];
  const float* b0   = (const float*)d_in[7];
  const float* Wi1  = (const float*)d_in[8];
  const float* Wh1  = (const float*)d_in[9];
  const float* b1   = (const float*)d_in[10];
  const float* Wv0  = (const float*)d_in[11];
  const float* bv0  = (const float*)d_in[12];
  const float* Wv1  = (const float*)d_in[13];
  const float* bv1  = (const float*)d_in[14];
  const float* Wv2  = (const float*)d_in[15];
  const float* bv2  = (const float*)d_in[16];
  const float* Wm0  = (const float*)d_in[17];
  const float* bm0  = (const float*)d_in[18];
  const float* Wm1  = (const float*)d_in[19];
  const float* bm1  = (const float*)d_in[20];
  const float* Wm2  = (const float*)d_in[21];
  const float* bm2  = (const float*)d_in[22];
  const float* lstd = (const float*)d_in[23];
  float* out = (float*)d_out;
  char* ws = (char*)d_ws;

  u32* bar0 = (u32*)(ws + WS_BAR);
  u32* bar1 = (u32*)(ws + WS_BAR + 8192);
  u16* xT   = (u16*)(ws + WS_XT);
  u16* ys0  = (u16*)(ws + WS_YS0);
  u16* ys1  = (u16*)(ws + WS_YS1);
  u16* hb0  = (u16*)(ws + WS_HB0);
  u16* hb1  = (u16*)(ws + WS_HB1);
  float* P  = (float*)(ws + WS_P);
  u16* H0M  = (u16*)(ws + WS_H0M);
  u16* V1M  = (u16*)(ws + WS_V1M);

  hipMemsetAsync(ws + WS_BAR, 0, 16384, stream);
  convert_x_kernel<<<4096, 256, 0, stream>>>(x, xT);
  lstm_kernel<128><<<16, 256, 0, stream>>>(xT, Wi0, Wh0, b0, c0, h0, hb0, ys0,
                                           out + 1160, out + 33928, bar0);
  lstm_kernel<256><<<16, 256, 0, stream>>>(ys0, Wi1, Wh1, b1, c1, h1, hb1, ys1,
                                           out + 66696, out + 99464, bar1);
  head_gemm_kernel<<<512, 256, 0, stream>>>(ys1, Wv0, Wm0, P);
  head_reduce_kernel<<<512, 256, 0, stream>>>(P, bv0, bm0, H0M);
  head_mid_kernel<<<16, 256, 0, stream>>>(H0M, Wv1, Wm1, bv1, bm1, V1M);
  head_final_kernel<<<1, 1024, 0, stream>>>(V1M, Wv2, bv2, Wm2, bm2, lstd, out);
}

// Round 3
// 2975.960 us; speedup vs baseline: 2.0002x; 2.0002x over previous
//
#include <hip/hip_runtime.h>

// ---------------------------------------------------------------------------
// RecurrentActorCritic on MI355X.  B=128, T=256, F=128, H=256, 4H=1024, W=512, A=8.
// d_out (float): mean[1024] | log_std[8] | value[128] | c0n | h0n | c1n | h1n
// ---------------------------------------------------------------------------

typedef __attribute__((ext_vector_type(8))) short  frag8;   // 8 bf16 (4 VGPR)
typedef __attribute__((ext_vector_type(4))) float  f32x4;
typedef unsigned short u16;
typedef unsigned int   u32;

// workspace layout (bytes)
#define WS_FLAGS 0                               // 8KB (32 flags, 128B stride)
#define WS_XT    8192                            // (T,B,F) bf16: 8.4MB
#define WS_W0B   (WS_XT + 128*256*128*2)         // Wi0 frag-layout bf16: 256KB
#define WS_W1B   (WS_W0B + 262144)               // Wi1 frag-layout bf16: 512KB
#define WS_YS0   (WS_W1B + 524288)               // (T,128,256) bf16: 16.8MB
#define WS_YS1   (WS_YS0 + 16777216)             // (T,128,256) bf16: 16.8MB
#define WS_H0M   (WS_YS1 + 16777216)             // (128,1024) bf16
#define WS_V1M   (WS_H0M + 262144)
#define WS_P     WS_XT                           // 16.8MB alias (xT/w*b/ys0 dead at head time)

__device__ __forceinline__ u16 f2b(float f) {
  u32 u = __builtin_bit_cast(u32, f);
  u32 r = (u + 0x7fffu + ((u >> 16) & 1u)) >> 16;   // RNE
  return (u16)r;
}
__device__ __forceinline__ float b2f(u16 b) {
  return __builtin_bit_cast(float, (u32)b << 16);
}
__device__ __forceinline__ float sigm(float x) { return 1.0f / (1.0f + __expf(-x)); }
__device__ __forceinline__ float tanh_(float x) {
  x = fminf(fmaxf(x, -15.0f), 15.0f);
  float e = __expf(2.0f * x);
  return (e - 1.0f) / (e + 1.0f);
}

// ---- system-scope (MALL) memory ops: bypass L1/L2, no cache-maintenance ---
__device__ __forceinline__ frag8 coh16(const u16* p) {
  frag8 r;
  asm volatile("global_load_dwordx4 %0, %1, off sc0 sc1" : "=v"(r) : "v"(p) : "memory");
  return r;
}
__device__ __forceinline__ void coh_st32(u16* p, u32 v) {
  asm volatile("global_store_dword %0, %1, off sc0 sc1" :: "v"(p), "v"(v) : "memory");
}
__device__ __forceinline__ void coh_stf(u32* p, u32 v) {
  asm volatile("global_store_dword %0, %1, off sc0 sc1" :: "v"(p), "v"(v) : "memory");
}
__device__ __forceinline__ u32 coh_ld32(const u32* p) {
  u32 r;
  asm volatile("global_load_dword %0, %1, off sc0 sc1\n\t"
               "s_waitcnt vmcnt(0)" : "=v"(r) : "v"(p) : "memory");
  return r;
}
__device__ __forceinline__ void waitall() {
  asm volatile("s_waitcnt vmcnt(0)" ::: "memory");
  __builtin_amdgcn_sched_barrier(0);   // rule #18: pin MFMA below the wait
}

// post: all waves drain their coherent stores, then one flag store
__device__ __forceinline__ void postflag(u32* flagp, u32 val) {
  asm volatile("s_waitcnt vmcnt(0)" ::: "memory");
  __syncthreads();
  if (threadIdx.x == 0) coh_stf(flagp, val);
}
// wave-0 lanes poll per-lane (pointer,target); lanes beyond range poll dups
__device__ __forceinline__ void waitflags_lane(const u32* p, u32 target) {
  if (threadIdx.x < 64) {
    while (true) {
      u32 v = coh_ld32(p);
      if (!__any(v < target)) break;
      __builtin_amdgcn_s_sleep(1);
    }
  }
  __syncthreads();
}

// ---------------- K0: x (B,T,F) f32 -> xT (T,B,F) bf16 ---------------------
__global__ void convert_x_kernel(const float* __restrict__ x, u16* __restrict__ xT) {
  int g = blockIdx.x * 256 + threadIdx.x;
  int f4 = g & 31, rem = g >> 5;                   // rem = t*128 + b
  int t = rem >> 7, b = rem & 127;
  const float4 v = *reinterpret_cast<const float4*>(x + ((size_t)(b * 256 + t)) * 128 + f4 * 4);
  ushort4 ov;
  ov.x = f2b(v.x); ov.y = f2b(v.y); ov.z = f2b(v.z); ov.w = f2b(v.w);
  *reinterpret_cast<ushort4*>(xT + (size_t)rem * 128 + f4 * 4) = ov;
}

// ---------------- Wi -> bf16 MFMA-fragment-layout buffers ------------------
// frag index fi = ((blk*4 + tile)*NKX + kt)*64 + lane ; 8 bf16 each.
__global__ void wxb_kernel(const float* __restrict__ Wi0, const float* __restrict__ Wi1,
                           u16* __restrict__ w0b, u16* __restrict__ w1b) {
  int g = blockIdx.x * 256 + threadIdx.x;          // 49152 frags total
  const float* W; u16* dst; int NKX, fi;
  if (g < 16384) { W = Wi0; dst = w0b; NKX = 4; fi = g; }
  else           { W = Wi1; dst = w1b; NKX = 8; fi = g - 16384; }
  int l = fi & 63; int rest = fi >> 6;
  int kt = rest % NKX; rest /= NKX;
  int tile = rest & 3; int blk = rest >> 2;
  int gcol = tile * 256 + blk * 16 + (l & 15);
  int k0 = kt * 32 + (l >> 4) * 8;
#pragma unroll
  for (int j = 0; j < 8; ++j)
    dst[(size_t)fi * 8 + j] = f2b(W[(size_t)(k0 + j) * 1024 + gcol]);
}

// ---------------- fused persistent 2-layer LSTM ----------------------------
// 32 blocks: 0..15 = layer0 (hd slice 16 each), 16..31 = layer1 (1 step behind).
// flags[g] = number of completed steps of block g.
// L0 step t>0 : wait flags[0..15]  >= t
// L1 step t   : wait flags[0..15] >= t+1  AND  flags[16..31] >= t
template <int NKX, bool XCOH, int LAYER>
__device__ __forceinline__ void lstm_body(
    const u16* __restrict__ xsrc, int xstride, const u16* __restrict__ wxb,
    const float* __restrict__ Wh, const float* __restrict__ bias,
    const float* __restrict__ cin, const float* __restrict__ hin,
    u16* __restrict__ ys, float* __restrict__ cOut, float* __restrict__ hOut,
    u32* __restrict__ flags, int blk) {
  const int tid = threadIdx.x, wv = tid >> 6, l = tid & 63;
  const int cl = l & 15, lk8 = (l >> 4) * 8;
  const int hdb = blk * 16, hd = hdb + cl;
  u32* flagSelf = flags + (LAYER * 16 + blk) * 32;

  // per-lane poll slot
  const int pidx = (LAYER == 0) ? (l & 15) : (l & 31);
  const u32* pollp = flags + pidx * 32;

  // resident Wh fragments (bf16, frag layout)
  frag8 wh[4][8];
#pragma unroll
  for (int g = 0; g < 4; ++g) {
    int gcol = g * 256 + hdb + cl;
#pragma unroll
    for (int kt = 0; kt < 8; ++kt) {
      frag8 f;
#pragma unroll
      for (int j = 0; j < 8; ++j)
        f[j] = (short)f2b(Wh[(size_t)(kt * 32 + lk8 + j) * 1024 + gcol]);
      wh[g][kt] = f;
    }
  }
  float bi[4];
#pragma unroll
  for (int g = 0; g < 4; ++g) bi[g] = bias[g * 256 + hdb + cl];
  float cst[2][4];
#pragma unroll
  for (int rt = 0; rt < 2; ++rt)
#pragma unroll
    for (int r = 0; r < 4; ++r)
      cst[rt][r] = cin[(wv * 32 + rt * 16 + (l >> 4) * 4 + r) * 256 + hd];

#pragma unroll 1
  for (int t = 0; t < 256; ++t) {
    if (LAYER == 1) {
      u32 tgt = ((l & 31) < 16) ? (u32)(t + 1) : (u32)t;
      waitflags_lane(pollp, tgt);
    } else if (t > 0) {
      waitflags_lane(pollp, (u32)t);
    }

    frag8 xa[2][NKX], ha[2][8];
    {
      const u16* xb = xsrc + (size_t)t * 128 * xstride;
#pragma unroll
      for (int rt = 0; rt < 2; ++rt) {
        int arow = wv * 32 + rt * 16 + cl;
#pragma unroll
        for (int kt = 0; kt < NKX; ++kt) {
          const u16* p = xb + (size_t)arow * xstride + kt * 32 + lk8;
          if (XCOH) xa[rt][kt] = coh16(p);
          else      xa[rt][kt] = *reinterpret_cast<const frag8*>(p);
        }
      }
    }
    if (t == 0) {
#pragma unroll
      for (int rt = 0; rt < 2; ++rt) {
        int arow = wv * 32 + rt * 16 + cl;
        const float* hp = hin + arow * 256;
#pragma unroll
        for (int kt = 0; kt < 8; ++kt) {
          const float* p = hp + kt * 32 + lk8;
          float4 q0 = *(const float4*)p, q1 = *(const float4*)(p + 4);
          frag8 f;
          f[0] = (short)f2b(q0.x); f[1] = (short)f2b(q0.y);
          f[2] = (short)f2b(q0.z); f[3] = (short)f2b(q0.w);
          f[4] = (short)f2b(q1.x); f[5] = (short)f2b(q1.y);
          f[6] = (short)f2b(q1.z); f[7] = (short)f2b(q1.w);
          ha[rt][kt] = f;
        }
      }
    } else {
      const u16* hb = ys + ((size_t)(t - 1) << 15);
#pragma unroll
      for (int rt = 0; rt < 2; ++rt) {
        int arow = wv * 32 + rt * 16 + cl;
#pragma unroll
        for (int kt = 0; kt < 8; ++kt)
          ha[rt][kt] = coh16(hb + arow * 256 + kt * 32 + lk8);
      }
    }
    waitall();

    f32x4 acc[4][2];
#pragma unroll
    for (int g = 0; g < 4; ++g)
#pragma unroll
      for (int rt = 0; rt < 2; ++rt)
        acc[g][rt] = f32x4{bi[g], bi[g], bi[g], bi[g]};

    // phase 1: x-part, streamed Wi fragments (L2-resident, read-only)
#pragma unroll
    for (int kt = 0; kt < NKX; ++kt)
#pragma unroll
      for (int g = 0; g < 4; ++g) {
        frag8 wf = *(const frag8*)(wxb + ((((size_t)blk * 4 + g) * NKX + kt) * 64 + l) * 8);
        acc[g][0] = __builtin_amdgcn_mfma_f32_16x16x32_bf16(xa[0][kt], wf, acc[g][0], 0, 0, 0);
        acc[g][1] = __builtin_amdgcn_mfma_f32_16x16x32_bf16(xa[1][kt], wf, acc[g][1], 0, 0, 0);
      }
    // phase 2: h-part, resident Wh
#pragma unroll
    for (int kt = 0; kt < 8; ++kt)
#pragma unroll
      for (int g = 0; g < 4; ++g) {
        acc[g][0] = __builtin_amdgcn_mfma_f32_16x16x32_bf16(ha[0][kt], wh[g][kt], acc[g][0], 0, 0, 0);
        acc[g][1] = __builtin_amdgcn_mfma_f32_16x16x32_bf16(ha[1][kt], wh[g][kt], acc[g][1], 0, 0, 0);
      }

    // gate math + coherent h store (u32-packed via lane^1)
    u16* yd = ys + ((size_t)t << 15);
#pragma unroll
    for (int rt = 0; rt < 2; ++rt)
#pragma unroll
      for (int r = 0; r < 4; ++r) {
        int row = wv * 32 + rt * 16 + (l >> 4) * 4 + r;
        float zi = acc[0][rt][r], zf = acc[1][rt][r];
        float zg = acc[2][rt][r], zo = acc[3][rt][r];
        float cn = sigm(zf) * cst[rt][r] + sigm(zi) * tanh_(zg);
        float hn = sigm(zo) * tanh_(cn);
        cst[rt][r] = cn;
        u32 hb16 = (u32)f2b(hn);
        u32 pr = (u32)__shfl_xor((int)hb16, 1);
        if ((cl & 1) == 0)
          coh_st32(yd + row * 256 + hd, hb16 | (pr << 16));
        if (t == 255) {
          cOut[row * 256 + hd] = cn;
          hOut[row * 256 + hd] = hn;
        }
      }
    postflag(flagSelf, (u32)(t + 1));
  }
}

__launch_bounds__(256, 1)
__global__ void lstm_fused(const u16* __restrict__ xT,
                           const u16* __restrict__ w0b, const u16* __restrict__ w1b,
                           const float* __restrict__ Wh0, const float* __restrict__ b0,
                           const float* __restrict__ c0, const float* __restrict__ h0,
                           const float* __restrict__ Wh1, const float* __restrict__ b1,
                           const float* __restrict__ c1, const float* __restrict__ h1,
                           u16* __restrict__ ys0, u16* __restrict__ ys1,
                           float* __restrict__ out, u32* __restrict__ flags) {
  const int gid = blockIdx.x;
  if (gid < 16)
    lstm_body<4, false, 0>(xT, 128, w0b, Wh0, b0, c0, h0, ys0,
                           out + 1160, out + 33928, flags, gid);
  else
    lstm_body<8, true, 1>(ys0, 256, w1b, Wh1, b1, c1, h1, ys1,
                          out + 66696, out + 99464, flags, gid - 16);
}

// ---------------- heads (validated in round 1) -----------------------------
__launch_bounds__(256, 2)
__global__ void head_gemm_kernel(const u16* __restrict__ flatT,
                                 const float* __restrict__ Wv0,
                                 const float* __restrict__ Wm0,
                                 float* __restrict__ P) {
  const int bx = blockIdx.x;
  const int nb = bx >> 5, kb = bx & 31;
  const float* W = (nb >> 3) ? Wm0 : Wv0;
  const int ncb = (nb & 7) * 64;
  const int tid = threadIdx.x;
  const int wv = tid >> 6, l = tid & 63;
  const int lrow = l & 15, lk = (l >> 4) * 8;
  f32x4 acc[2][4] = {};
  const int kbase = kb * 2048;
#pragma unroll 2
  for (int ks = 0; ks < 64; ++ks) {
    int k0 = kbase + ks * 32;
    int t = k0 >> 8, h = k0 & 255;
    frag8 a[2];
#pragma unroll
    for (int mi = 0; mi < 2; ++mi) {
      int row = (2 * wv + mi) * 16 + lrow;
      a[mi] = *reinterpret_cast<const frag8*>(flatT + ((size_t)t * 128 + row) * 256 + h + lk);
    }
#pragma unroll
    for (int nt = 0; nt < 4; ++nt) {
      int col = ncb + nt * 16 + lrow;
      const float* wp = W + (size_t)(k0 + lk) * 512 + col;
      frag8 bfrag;
#pragma unroll
      for (int j = 0; j < 8; ++j) bfrag[j] = (short)f2b(wp[(size_t)j * 512]);
      acc[0][nt] = __builtin_amdgcn_mfma_f32_16x16x32_bf16(a[0], bfrag, acc[0][nt], 0, 0, 0);
      acc[1][nt] = __builtin_amdgcn_mfma_f32_16x16x32_bf16(a[1], bfrag, acc[1][nt], 0, 0, 0);
    }
  }
  float* Pb = P + (size_t)bx * 8192;
#pragma unroll
  for (int mi = 0; mi < 2; ++mi)
#pragma unroll
    for (int nt = 0; nt < 4; ++nt)
#pragma unroll
      for (int r = 0; r < 4; ++r) {
        int row = (2 * wv + mi) * 16 + (l >> 4) * 4 + r;
        int nl = nt * 16 + lrow;
        Pb[row * 64 + nl] = acc[mi][nt][r];
      }
}

__global__ void head_reduce_kernel(const float* __restrict__ P,
                                   const float* __restrict__ bv0,
                                   const float* __restrict__ bm0,
                                   u16* __restrict__ H0) {
  int o = blockIdx.x * 256 + threadIdx.x;
  int row = o >> 10, gcol = o & 1023;
  int nb = gcol >> 6, nl = gcol & 63;
  float s = 0.f;
#pragma unroll
  for (int kb = 0; kb < 32; ++kb)
    s += P[(size_t)(nb * 32 + kb) * 8192 + row * 64 + nl];
  s += (gcol < 512) ? bv0[gcol] : bm0[gcol - 512];
  H0[row * 1024 + gcol] = f2b(tanh_(s));
}

__launch_bounds__(256, 2)
__global__ void head_mid_kernel(const u16* __restrict__ H0,
                                const float* __restrict__ Wv1,
                                const float* __restrict__ Wm1,
                                const float* __restrict__ bv1,
                                const float* __restrict__ bm1,
                                u16* __restrict__ V1M) {
  const int nb = blockIdx.x;
  const int head = nb >> 3;
  const int ncb = (nb & 7) * 64;
  const float* W = head ? Wm1 : Wv1;
  const float* bsrc = head ? bm1 : bv1;
  const int tid = threadIdx.x, wv = tid >> 6, l = tid & 63;
  const int lrow = l & 15, lk = (l >> 4) * 8;
  const int aoff = head * 512;
  f32x4 acc[2][4] = {};
#pragma unroll 2
  for (int ks = 0; ks < 16; ++ks) {
    int k0 = ks * 32;
    frag8 a[2];
#pragma unroll
    for (int mi = 0; mi < 2; ++mi) {
      int row = (2 * wv + mi) * 16 + lrow;
      a[mi] = *reinterpret_cast<const frag8*>(H0 + row * 1024 + aoff + k0 + lk);
    }
#pragma unroll
    for (int nt = 0; nt < 4; ++nt) {
      int col = ncb + nt * 16 + lrow;
      const float* wp = W + (size_t)(k0 + lk) * 512 + col;
      frag8 bfrag;
#pragma unroll
      for (int j = 0; j < 8; ++j) bfrag[j] = (short)f2b(wp[(size_t)j * 512]);
      acc[0][nt] = __builtin_amdgcn_mfma_f32_16x16x32_bf16(a[0], bfrag, acc[0][nt], 0, 0, 0);
      acc[1][nt] = __builtin_amdgcn_mfma_f32_16x16x32_bf16(a[1], bfrag, acc[1][nt], 0, 0, 0);
    }
  }
#pragma unroll
  for (int mi = 0; mi < 2; ++mi)
#pragma unroll
    for (int nt = 0; nt < 4; ++nt)
#pragma unroll
      for (int r = 0; r < 4; ++r) {
        int row = (2 * wv + mi) * 16 + (l >> 4) * 4 + r;
        int cl = ncb + nt * 16 + lrow;
        float z = acc[mi][nt][r] + bsrc[cl];
        V1M[row * 1024 + head * 512 + cl] = f2b(tanh_(z));
      }
}

__global__ void head_final_kernel(const u16* __restrict__ V1M,
                                  const float* __restrict__ Wv2,
                                  const float* __restrict__ bv2,
                                  const float* __restrict__ Wm2,
                                  const float* __restrict__ bm2,
                                  const float* __restrict__ log_std,
                                  float* __restrict__ out) {
  int tid = threadIdx.x;   // 1024 threads
  {
    int row = tid >> 3, a = tid & 7;
    float s = 0.f;
    for (int k = 0; k < 512; ++k)
      s += b2f(V1M[row * 1024 + 512 + k]) * Wm2[k * 8 + a];
    out[row * 8 + a] = s + bm2[a];
  }
  if (tid < 128) {
    float s = 0.f;
    for (int k = 0; k < 512; ++k)
      s += b2f(V1M[tid * 1024 + k]) * Wv2[k];
    out[1032 + tid] = s + bv2[0];
  }
  if (tid < 8) out[1024 + tid] = log_std[tid];
}

// ---------------------------------------------------------------------------
extern "C" void kernel_launch(void* const* d_in, const int* in_sizes, int n_in,
                              void* d_out, int out_size, void* d_ws, size_t ws_size,
                              hipStream_t stream) {
  const float* x    = (const float*)d_in[0];
  const float* c0   = (const float*)d_in[1];
  const float* h0   = (const float*)d_in[2];
  const float* c1   = (const float*)d_in[3];
  const float* h1   = (const float*)d_in[4];
  const float* Wi0  = (const float*)d_in[5];
  const float* Wh0  = (const float*)d_in[6];
  const float* b0   = (const float*)d_in[7];
  const float* Wi1  = (const float*)d_in[8];
  const float* Wh1  = (const float*)d_in[9];
  const float* b1   = (const float*)d_in[10];
  const float* Wv0  = (const float*)d_in[11];
  const float* bv0  = (const float*)d_in[12];
  const float* Wv1  = (const float*)d_in[13];
  const float* bv1  = (const float*)d_in[14];
  const float* Wv2  = (const float*)d_in[15];
  const float* bv2  = (const float*)d_in[16];
  const float* Wm0  = (const float*)d_in[17];
  const float* bm0  = (const float*)d_in[18];
  const float* Wm1  = (const float*)d_in[19];
  const float* bm1  = (const float*)d_in[20];
  const float* Wm2  = (const float*)d_in[21];
  const float* bm2  = (const float*)d_in[22];
  const float* lstd = (const float*)d_in[23];
  float* out = (float*)d_out;
  char* ws = (char*)d_ws;

  u32* flags = (u32*)(ws + WS_FLAGS);
  u16* xT    = (u16*)(ws + WS_XT);
  u16* w0b   = (u16*)(ws + WS_W0B);
  u16* w1b   = (u16*)(ws + WS_W1B);
  u16* ys0   = (u16*)(ws + WS_YS0);
  u16* ys1   = (u16*)(ws + WS_YS1);
  float* P   = (float*)(ws + WS_P);
  u16* H0M   = (u16*)(ws + WS_H0M);
  u16* V1M   = (u16*)(ws + WS_V1M);

  hipMemsetAsync(ws + WS_FLAGS, 0, 8192, stream);
  convert_x_kernel<<<4096, 256, 0, stream>>>(x, xT);
  wxb_kernel<<<192, 256, 0, stream>>>(Wi0, Wi1, w0b, w1b);
  lstm_fused<<<32, 256, 0, stream>>>(xT, w0b, w1b, Wh0, b0, c0, h0,
                                     Wh1, b1, c1, h1, ys0, ys1, out, flags);
  head_gemm_kernel<<<512, 256, 0, stream>>>(ys1, Wv0, Wm0, P);
  head_reduce_kernel<<<512, 256, 0, stream>>>(P, bv0, bm0, H0M);
  head_mid_kernel<<<16, 256, 0, stream>>>(H0M, Wv1, Wm1, bv1, bm1, V1M);
  head_final_kernel<<<1, 1024, 0, stream>>>(V1M, Wv2, bv2, Wm2, bm2, lstd, out);
}